// Round 6
// baseline (74.450 us; speedup 1.0000x reference)
//
#include <hip/hip_runtime.h>
#include <hip/hip_bf16.h>

typedef __attribute__((ext_vector_type(8))) short short8;
typedef __attribute__((ext_vector_type(4))) float floatx4;

#define B_SZ   64
#define N_TOK  32
#define S_TOK  1024
#define D_DIM  128
#define ALPHA  0.3f

#define STRIP_S     32
#define STRIP_EL    (STRIP_S * D_DIM)       // 4096 elements
#define STRIP_BYTES (STRIP_EL * 2)          // 8192 B
#define NSTRIP      (S_TOK / STRIP_S)       // 32
#define NBUF        6                       // prefetch depth 3, reuse distance 3
#define C_EL        (S_TOK * D_DIM)         // 131072 elements per doc batch

#define DBLK (B_SZ * S_TOK * D_DIM / 8 / 256)   // 4096 blocks for D part
#define QBLK (B_SZ * N_TOK * D_DIM / 8 / 256)   // 128 blocks for Q part

#define WAITV_(N) asm volatile("s_waitcnt vmcnt(" #N ")" ::: "memory")
#define WAITV(N)  WAITV_(N)

__device__ __forceinline__ short f2bf(float f) {
    __hip_bfloat16 h = __float2bfloat16(f);
    return __builtin_bit_cast(short, h);
}

__device__ __forceinline__ short8 cvt8(const float* __restrict__ p) {
    floatx4 f0 = *reinterpret_cast<const floatx4*>(p);
    floatx4 f1 = *reinterpret_cast<const floatx4*>(p + 4);
    short8 r;
    r[0] = f2bf(f0[0]); r[1] = f2bf(f0[1]); r[2] = f2bf(f0[2]); r[3] = f2bf(f0[3]);
    r[4] = f2bf(f1[0]); r[5] = f2bf(f1[1]); r[6] = f2bf(f1[2]); r[7] = f2bf(f1[3]);
    return r;
}

// One launch converts everything. grid (DBLK + QBLK, 2).
// D part: fp32 -> bf16 with fragment permutation:
//   dst pos = c*C_EL + st*STRIP_EL + (ks*2+nt)*512 + (lg*16+lr)*8
//   where s = st*32 + nt*16 + lr, k = ks*32 + lg*8.
// Q part: plain layout-preserving fp32 -> bf16.
__global__ __launch_bounds__(256) void cvt_all_kernel(
    const float* __restrict__ q,  const float* __restrict__ d,
    const float* __restrict__ tq, const float* __restrict__ td,
    __hip_bfloat16* __restrict__ qb,  __hip_bfloat16* __restrict__ db,
    __hip_bfloat16* __restrict__ tqb, __hip_bfloat16* __restrict__ tdb) {
    const int which = blockIdx.y;
    if (blockIdx.x >= DBLK) {
        const float* src = which ? tq : q;
        __hip_bfloat16* dst = which ? tqb : qb;
        int idx = (blockIdx.x - DBLK) * 256 + threadIdx.x;
        *reinterpret_cast<short8*>(dst + (size_t)idx * 8) = cvt8(src + (size_t)idx * 8);
    } else {
        const float* src = which ? td : d;
        __hip_bfloat16* dst = which ? tdb : db;
        int idx = blockIdx.x * 256 + threadIdx.x;
        int kc = idx & 15;            // k-chunk 0..15
        int s  = (idx >> 4) & (S_TOK - 1);
        int c  = idx >> 14;
        int st = s >> 5, nt = (s >> 4) & 1, lr = s & 15;
        int ks = kc >> 2, lg = kc & 3;
        size_t dpos = (size_t)c * C_EL + (size_t)st * STRIP_EL
                    + (size_t)(ks * 2 + nt) * 512 + (size_t)(lg * 16 + lr) * 8;
        *reinterpret_cast<short8*>(dst + dpos) = cvt8(src + (size_t)idx * 8);
    }
}

__device__ __forceinline__ void gload_lds16(const void* g, void* l) {
    __builtin_amdgcn_global_load_lds(
        (const __attribute__((address_space(1))) unsigned int*)g,
        (__attribute__((address_space(3))) unsigned int*)l, 16, 0, 0);
}

// Grid: (c = 64, bg = 4, which = 2) = 512 blocks (2/CU), 256 threads (4 waves).
// Wave w owns 4 batches b0 = bg*16 + w*4 .. +3 (M = 128 rows per wave).
// D[c] strips staged to LDS (permuted layout), 6-deep ring, depth-3 prefetch,
// counted vmcnt + raw s_barrier (never drains the pipeline).
__global__ __launch_bounds__(256, 2) void maxsim_scores_kernel(
    const __hip_bfloat16* __restrict__ qb,  const __hip_bfloat16* __restrict__ db,
    const __hip_bfloat16* __restrict__ tqb, const __hip_bfloat16* __restrict__ tdb,
    float* __restrict__ scores_ws /* [2][64][64] */) {

    const int c     = blockIdx.x;
    const int bg    = blockIdx.y;
    const int which = blockIdx.z;
    const __hip_bfloat16* Q = which ? tqb : qb;
    const __hip_bfloat16* D = which ? tdb : db;
    float* out = scores_ws + which * (B_SZ * B_SZ);

    const int tid = threadIdx.x;
    const int w   = tid >> 6;     // wave 0..3
    const int l   = tid & 63;     // lane
    const int lg  = l >> 4;       // k-subrange 0..3
    const int lr  = l & 15;       // row/col within 16

    const int b0 = bg * 16 + w * 4;

    __shared__ __align__(16) char smem[NBUF * STRIP_BYTES];  // 48 KB ring

    // A fragments: mt 0..7 -> batch b0 + (mt>>1), row (mt&1)*16 + lr. 128 VGPR.
    short8 afrag[8][4];
#pragma unroll
    for (int mt = 0; mt < 8; ++mt)
#pragma unroll
        for (int ks = 0; ks < 4; ++ks)
            afrag[mt][ks] = *reinterpret_cast<const short8*>(
                Q + ((size_t)(b0 + (mt >> 1)) * N_TOK + (mt & 1) * 16 + lr) * D_DIM
                  + ks * 32 + lg * 8);
    // Pin afrag in VGPRs: forbid the compiler from sinking/rematerializing
    // the loads into the strip loop (r4/r5 showed VGPR_Count < afrag size).
#pragma unroll
    for (int mt = 0; mt < 8; ++mt)
#pragma unroll
        for (int ks = 0; ks < 4; ++ks)
            asm volatile("" : "+v"(afrag[mt][ks]));

    float runmax[8][4];
#pragma unroll
    for (int mt = 0; mt < 8; ++mt)
#pragma unroll
        for (int j = 0; j < 4; ++j) runmax[mt][j] = -INFINITY;

    const char* gstrip = (const char*)(D + (size_t)c * C_EL);
    const unsigned y0 = tid * 16;
    const unsigned y1 = 4096 + tid * 16;

    // Prologue: stage strips 0..2 into buffers 0..2.
#pragma unroll
    for (int p = 0; p < 3; ++p) {
        gload_lds16(gstrip + p * STRIP_BYTES + y0, smem + p * STRIP_BYTES + y0);
        gload_lds16(gstrip + p * STRIP_BYTES + y1, smem + p * STRIP_BYTES + y1);
    }

    auto compute = [&](const char* bufc) {
#pragma unroll
        for (int nt = 0; nt < 2; ++nt) {
            short8 bf[4];
#pragma unroll
            for (int ks = 0; ks < 4; ++ks)
                bf[ks] = *reinterpret_cast<const short8*>(
                    bufc + (ks * 2 + nt) * 1024 + l * 16);

            floatx4 acc[8];
#pragma unroll
            for (int mt = 0; mt < 8; ++mt) acc[mt] = floatx4{0.f, 0.f, 0.f, 0.f};

#pragma unroll
            for (int ks = 0; ks < 4; ++ks)
#pragma unroll
                for (int mt = 0; mt < 8; ++mt)
                    acc[mt] = __builtin_amdgcn_mfma_f32_16x16x32_bf16(
                        afrag[mt][ks], bf[ks], acc[mt], 0, 0, 0);

#pragma unroll
            for (int mt = 0; mt < 8; ++mt)
#pragma unroll
                for (int j = 0; j < 4; ++j)
                    runmax[mt][j] = fmaxf(runmax[mt][j], acc[mt][j]);
        }
    };

    // Main loop: issue strip st+3, wait for strip st (6 newer loads allowed),
    // barrier, compute. Ring distance 3 > max wave skew 1 -> no WAR race.
    for (int st = 0; st < NSTRIP - 3; ++st) {
        const int tb = (st + 3) % NBUF;
        const char* gs = gstrip + (size_t)(st + 3) * STRIP_BYTES;
        gload_lds16(gs + y0, smem + tb * STRIP_BYTES + y0);
        gload_lds16(gs + y1, smem + tb * STRIP_BYTES + y1);
        WAITV(6);
        __builtin_amdgcn_s_barrier();
        compute(smem + (st % NBUF) * STRIP_BYTES);
    }
    // Tail: strips 29, 30, 31 (no new issues; drain 4 -> 2 -> 0).
    WAITV(4);
    __builtin_amdgcn_s_barrier();
    compute(smem + ((NSTRIP - 3) % NBUF) * STRIP_BYTES);
    WAITV(2);
    __builtin_amdgcn_s_barrier();
    compute(smem + ((NSTRIP - 2) % NBUF) * STRIP_BYTES);
    WAITV(0);
    __builtin_amdgcn_s_barrier();
    compute(smem + ((NSTRIP - 1) % NBUF) * STRIP_BYTES);

    // Max over the 16 s-columns spread across lr.
#pragma unroll
    for (int mt = 0; mt < 8; ++mt)
#pragma unroll
        for (int j = 0; j < 4; ++j) {
            float v = runmax[mt][j];
            v = fmaxf(v, __shfl_xor(v, 1));
            v = fmaxf(v, __shfl_xor(v, 2));
            v = fmaxf(v, __shfl_xor(v, 4));
            v = fmaxf(v, __shfl_xor(v, 8));
            runmax[mt][j] = v;
        }

    // Per-batch row sums: batch b0+p covers mt = 2p, 2p+1 (rows lg*4+j).
#pragma unroll
    for (int p = 0; p < 4; ++p) {
        float s = 0.f;
#pragma unroll
        for (int j = 0; j < 4; ++j) s += runmax[2 * p][j] + runmax[2 * p + 1][j];
        s += __shfl_xor(s, 16);
        s += __shfl_xor(s, 32);
        if (l == 0) out[(b0 + p) * B_SZ + c] = s;
    }
}

// 1 block, 64 threads: final loss.
__global__ void loss_kernel(const float* __restrict__ scores_ws, float* __restrict__ out) {
    const float* sc = scores_ws;                 // student [64][64]
    const float* tc = scores_ws + B_SZ * B_SZ;   // teacher [64][64]
    const int b = threadIdx.x;                   // 0..63

    float pos = sc[b * B_SZ + b];
    float neg = -INFINITY;
    float msesum = 0.f;
#pragma unroll 8
    for (int cc = 0; cc < B_SZ; ++cc) {
        float s = sc[b * B_SZ + cc];
        float t = tc[b * B_SZ + cc];
        if (cc != b) neg = fmaxf(neg, s);
        _Float16 d16 = (_Float16)s - (_Float16)t;  // fp16 subtract (matches ref cast)
        _Float16 sq  = d16 * d16;                  // fp16 square
        msesum += (float)sq;                       // fp32 accumulation
    }
    float x = neg - pos;
    float sp = (x > 0.f) ? (x + log1pf(expf(-x))) : log1pf(expf(x));

#pragma unroll
    for (int m = 1; m < 64; m <<= 1) {
        sp     += __shfl_xor(sp, m);
        msesum += __shfl_xor(msesum, m);
    }
    if (b == 0) {
        float mse = msesum / 4096.f;
        mse = (float)(_Float16)mse;  // jnp.mean returns f16, then astype(f32)
        out[0] = sp / 64.f + ALPHA * mse;
    }
}

extern "C" void kernel_launch(void* const* d_in, const int* in_sizes, int n_in,
                              void* d_out, int out_size, void* d_ws, size_t ws_size,
                              hipStream_t stream) {
    const float* q  = (const float*)d_in[0];
    const float* d  = (const float*)d_in[1];
    const float* tq = (const float*)d_in[2];
    const float* td = (const float*)d_in[3];
    float* out = (float*)d_out;

    const size_t QN = (size_t)B_SZ * N_TOK * D_DIM;   // 262144
    const size_t DN = (size_t)B_SZ * S_TOK * D_DIM;   // 8388608

    float* scores_ws = (float*)d_ws;                                  // 32 KB
    __hip_bfloat16* qb  = (__hip_bfloat16*)((char*)d_ws + 32768);
    __hip_bfloat16* tqb = qb + QN;
    __hip_bfloat16* db  = tqb + QN;
    __hip_bfloat16* tdb = db + DN;

    cvt_all_kernel<<<dim3(DBLK + QBLK, 2), 256, 0, stream>>>(
        q, d, tq, td, qb, db, tqb, tdb);

    dim3 grid(B_SZ, B_SZ / 16, 2);
    maxsim_scores_kernel<<<grid, 256, 0, stream>>>(qb, db, tqb, tdb, scores_ws);
    loss_kernel<<<1, 64, 0, stream>>>(scores_ws, out);
}